// Round 8
// baseline (201.453 us; speedup 1.0000x reference)
//
#include <hip/hip_runtime.h>
#include <math.h>

#define LL 128
#define TT 11
#define NP 121            // T*T (y, y_prev) pairs
#define KK 7
#define GS 20             // sp group stride (floats); group g at [g*20 .. g*20+10], pad at +11
#define SPW 240           // 11 groups*20 + dummy slots 220..226
#define NSLOT 8           // E-pane LDS ring slots
#define PANEF 1024        // floats per E pane: [m=2][pair o=128][float4]

#define LOG2E 1.4426950408889634f
#define LN2   0.6931471805599453f

__device__ __forceinline__ float fast_exp2(float x) { return __builtin_amdgcn_exp2f(x); }
__device__ __forceinline__ float fast_log2(float x) { return __builtin_amdgcn_logf(x); }
#if __has_builtin(__builtin_amdgcn_rcpf)
__device__ __forceinline__ float fast_rcp(float x) { return __builtin_amdgcn_rcpf(x); }
#else
__device__ __forceinline__ float fast_rcp(float x) { return 1.0f / x; }
#endif
__device__ __forceinline__ float rfl(float x) {
    return __int_as_float(__builtin_amdgcn_readfirstlane(__float_as_int(x)));
}
__device__ __forceinline__ void cfence() { __builtin_amdgcn_wave_barrier(); }
#define VMWAIT28() asm volatile("s_waitcnt vmcnt(28)" ::: "memory")
#define VMWAIT0()  asm volatile("s_waitcnt vmcnt(0)"  ::: "memory")
#define LGKM0()    asm volatile("s_waitcnt lgkmcnt(0)" ::: "memory")

__device__ __forceinline__ void block_sync() {
    asm volatile("" ::: "memory");
    __builtin_amdgcn_s_barrier();
    asm volatile("" ::: "memory");
}

// ---------------------------------------------------------------------------
// Producer/consumer semi-CRF forward DP, v5: DUAL-BATCH consumer.
//
// Round-7 post-mortem: shuffle phase-2 REGRESSED (shfl = ds_permute = same
// in-order DS pipe, but serialized 5-deep on the chain). Round-6's sp LDS
// round-trip is the better machine; reverted to it verbatim.
//
// Round-6 residual: 574 cyc/step vs ~250 cyc intrinsic serial chain (FMA
// tree -> write/read pipe turnaround -> sum tree -> rcp -> W update). The
// chain cannot be shortened further, so v5 HIDES it: one consumer wave
// interleaves TWO independent batch elements (A, B). While A's phase-2
// reads are in flight, the wave issues B's work; the two serial chains
// overlap on one wave. Per-step math is bit-identical to round 6 per batch.
//
// Structure: grid = B/2 blocks x 320 threads (5 waves):
//   wave 0: dual-batch consumer (round-6 body duplicated, interleaved)
//   waves 1,2: producers for batch A (odd/even panes) -- round-6 verbatim
//   waves 3,4: producers for batch B (odd/even panes)
// LDS: ring[2][8][1024] (64 KB) + sp[2][240] (~2 KB).
// Tick = 4 DP steps, 32 barriers per wave (incl. B0), ring slots disjoint
// mod 8 between consumer reads (4t-3..4t) and producer writes (4t+1..4t+4).
// ---------------------------------------------------------------------------
__global__ __launch_bounds__(320, 1) void hscrf_pc5(const float* __restrict__ scores,
                                                    const int* __restrict__ mask,
                                                    float* __restrict__ out,
                                                    int n_batch)
{
    const int tid = threadIdx.x;
    const int l   = tid & 63;
    const int wid = tid >> 6;
    const int blk = blockIdx.x;

    __shared__ __align__(64) float ring[2][NSLOT][PANEF];   // 64 KB
    __shared__ __align__(64) float sp[2][SPW];

    const int bA = 2 * blk;
    const int bB = 2 * blk + 1;
    if (bA >= n_batch) return;

    const int o1  = l + 64;
    const bool val1 = (o1 < NP);
    const int o1c = val1 ? o1 : 0;

    if (wid >= 1) {
        // ============ PRODUCERS (round-6 verbatim, per batch/parity) =========
        const int bi = (wid - 1) >> 1;                    // 0: batch A, 1: batch B
        const int pw = (wid - 1) & 1;                     // pane parity
        const int bb = (2 * blk + bi < n_batch) ? (2 * blk + bi) : bA;
        const float* sb = scores + (size_t)bb * (size_t)(LL * (size_t)LL * NP);
        float (*myring)[PANEF] = ring[bi];

        float Xa0[KK], Xa1[KK], Xb0[KK], Xb1[KK];
        float Ya0[KK], Ya1[KK], Yb0[KK], Yb1[KK];

        // Coalesced gathers: pair o's raw score sits at slice[o] (o = yp*11+y).
        auto issue_pane = [&](int p, float (&a0)[KK], float (&a1)[KK]) {
#pragma unroll
            for (int k = 0; k < KK; ++k) {
                const int j = p - KK + k; const int jc = j < 0 ? 0 : j;
                const float* sl = sb + ((size_t)jc * LL + (size_t)(p - 1)) * NP;
                a0[k] = sl[l];                            // pairs 0..63
                a1[k] = sl[o1c];                          // pairs 64..120
            }
        };
        auto issue_pair = [&](int base, float (&a0)[KK], float (&a1)[KK],
                              float (&b0)[KK], float (&b1)[KK]) {
            issue_pane(base,     a0, a1);
            issue_pane(base + 2, b0, b1);
        };

        auto conv1 = [&](int p, const float (&a0)[KK], const float (&a1)[KK]) {
            const int slot = p & (NSLOT - 1);
            float v0[8], w1[8];
#pragma unroll
            for (int k = 0; k < KK; ++k) {
                const bool ok = (p - KK + k) >= 0;        // j >= 0 mask
                const float t0 = fast_exp2(a0[k] * LOG2E);
                const float t1 = fast_exp2(a1[k] * LOG2E);
                v0[k] = ok ? t0 : 0.0f;
                w1[k] = (ok && val1) ? t1 : 0.0f;         // o>=121 pairs -> 0
            }
            v0[7] = 0.0f; w1[7] = 0.0f;
            float4* dst = (float4*)&myring[slot][0];
            dst[l]       = make_float4(v0[0], v0[1], v0[2], v0[3]);
            dst[128 + l] = make_float4(v0[4], v0[5], v0[6], v0[7]);
            dst[64 + l]  = make_float4(w1[0], w1[1], w1[2], w1[3]);
            dst[192 + l] = make_float4(w1[4], w1[5], w1[6], w1[7]);
        };
        auto conv_pair = [&](int base, const float (&a0)[KK], const float (&a1)[KK],
                             const float (&b0)[KK], const float (&b1)[KK]) {
            conv1(base,     a0, a1);
            conv1(base + 2, b0, b1);
        };

        // Prologue: publish panes {1,3}+pw; leave {5,7}+pw in flight (buf X).
        issue_pair(1 + pw, Xa0, Xa1, Xb0, Xb1);
        VMWAIT0();                                        // one-time stall
        conv_pair(1 + pw, Xa0, Xa1, Xb0, Xb1);
        issue_pair(5 + pw, Xa0, Xa1, Xb0, Xb1);
        LGKM0(); block_sync();                            // B0: panes 1..4 live

        // Ticks 1..30: odd tick issue->Y conv X; even tick issue->X conv Y.
        for (int t = 1; t <= 29; t += 2) {
            issue_pair(4 * t + 5 + pw, Ya0, Ya1, Yb0, Yb1);
            VMWAIT28();
            conv_pair(4 * t + 1 + pw, Xa0, Xa1, Xb0, Xb1);
            LGKM0(); block_sync();

            issue_pair(4 * t + 9 + pw, Xa0, Xa1, Xb0, Xb1);
            VMWAIT28();
            conv_pair(4 * t + 5 + pw, Ya0, Ya1, Yb0, Yb1);
            LGKM0(); block_sync();
        }
        // Tick 31: drain; publish panes {125,127}+pw (buf X).
        VMWAIT0();
        conv_pair(125 + pw, Xa0, Xa1, Xb0, Xb1);
        LGKM0(); block_sync();                            // 32 barriers total
    } else {
        // ================= DUAL-BATCH CONSUMER ===============================
        // Relabeled decode (round-6): pair o = yp*11 + y.
        const int y0 = l % TT,   yp0 = l / TT;
        const int y1 = o1c % TT, yp1 = o1c / TT;
        const int i0w = y0 * GS + yp0;
        const int i1w = val1 ? (y1 * GS + yp1) : (220 + (l - 57));

        float* spA = sp[0];
        float* spB = sp[1];
        if (l < TT) { spA[l * GS + 11] = 0.0f; spB[l * GS + 11] = 0.0f; }

        const int mbA = mask[bA];
        const int mbB = (bB < n_batch) ? mask[bB] : mask[bA];

        float WA0[KK], WA1[KK], WB0[KK], WB1[KK];
#pragma unroll
        for (int k = 0; k < KK; ++k) { WA0[k] = 0.0f; WA1[k] = 0.0f;
                                       WB0[k] = 0.0f; WB1[k] = 0.0f; }
        const float w0init = (yp0 == TT - 1) ? 1.0f : 0.0f;         // never (yp0<=5)
        const float w1init = (val1 && yp1 == TT - 1) ? 1.0f : 0.0f;
        WA0[KK - 1] = w0init; WA1[KK - 1] = w1init;
        WB0[KK - 1] = w0init; WB1[KK - 1] = w1init;

        float CcA = 0.0f, CcB = 0.0f;
        float savedSA = 1.0f, savedCA = 0.0f;
        float savedSB = 1.0f, savedCB = 0.0f;

        struct E4 { float4 a0, a1, b0, b1; };
        E4 A_EA, A_EB, A_EC, B_EA, B_EB, B_EC;

        auto readPane = [&](const float (*rg)[PANEF], int p, E4& d) {
            const float4* b16 = (const float4*)&rg[p & (NSLOT - 1)][0];
            d.a0 = b16[l];      d.a1 = b16[128 + l];
            d.b0 = b16[64 + l]; d.b1 = b16[192 + l];
        };

        // One DP step for BOTH batches, interleaved (A's read latency hides
        // under B's issue and vice versa). Per-batch math == round 6 exactly.
        auto body2 = [&](int i, const E4& EA, const E4& EB) {
            // ---- phase 1 A ----
            float p0a = fmaf(EA.a0.x, WA0[0], EA.a0.y * WA0[1]);
            float q0a = fmaf(EA.a0.z, WA0[2], EA.a0.w * WA0[3]);
            float u0a = fmaf(EA.a1.x, WA0[4], EA.a1.y * WA0[5]);
            float s0a = (p0a + q0a) + fmaf(EA.a1.z, WA0[6], u0a);
            float p1a = fmaf(EA.b0.x, WA1[0], EA.b0.y * WA1[1]);
            float q1a = fmaf(EA.b0.z, WA1[2], EA.b0.w * WA1[3]);
            float u1a = fmaf(EA.b1.x, WA1[4], EA.b1.y * WA1[5]);
            float s1a = (p1a + q1a) + fmaf(EA.b1.z, WA1[6], u1a);
            spA[i0w] = s0a;
            spA[i1w] = s1a;
            // ---- phase 1 B ----
            float p0b = fmaf(EB.a0.x, WB0[0], EB.a0.y * WB0[1]);
            float q0b = fmaf(EB.a0.z, WB0[2], EB.a0.w * WB0[3]);
            float u0b = fmaf(EB.a1.x, WB0[4], EB.a1.y * WB0[5]);
            float s0b = (p0b + q0b) + fmaf(EB.a1.z, WB0[6], u0b);
            float p1b = fmaf(EB.b0.x, WB1[0], EB.b0.y * WB1[1]);
            float q1b = fmaf(EB.b0.z, WB1[2], EB.b0.w * WB1[3]);
            float u1b = fmaf(EB.b1.x, WB1[4], EB.b1.y * WB1[5]);
            float s1b = (p1b + q1b) + fmaf(EB.b1.z, WB1[6], u1b);
            spB[i0w] = s0b;
            spB[i1w] = s1b;

            cfence();                  // DS pipe in-order per wave

            // ---- phase 2 reads, A then B (B's issue hides under A's wait) ---
            const float4 qa0A = *(const float4*)(spA + yp0 * GS);
            const float4 qb0A = *(const float4*)(spA + yp0 * GS + 4);
            const float4 qc0A = *(const float4*)(spA + yp0 * GS + 8);
            const float4 qa1A = *(const float4*)(spA + yp1 * GS);
            const float4 qb1A = *(const float4*)(spA + yp1 * GS + 4);
            const float4 qc1A = *(const float4*)(spA + yp1 * GS + 8);
            const float4 qa0B = *(const float4*)(spB + yp0 * GS);
            const float4 qb0B = *(const float4*)(spB + yp0 * GS + 4);
            const float4 qc0B = *(const float4*)(spB + yp0 * GS + 8);
            const float4 qa1B = *(const float4*)(spB + yp1 * GS);
            const float4 qb1B = *(const float4*)(spB + yp1 * GS + 4);
            const float4 qc1B = *(const float4*)(spB + yp1 * GS + 8);

            // ---- sums A ----
            const float SAA = (((qa0A.x + qa0A.y) + (qa0A.z + qa0A.w)) +
                               ((qb0A.x + qb0A.y) + (qb0A.z + qb0A.w))) +
                              ((qc0A.x + qc0A.y) + (qc0A.z + qc0A.w));
            const float SBA = (((qa1A.x + qa1A.y) + (qa1A.z + qa1A.w)) +
                               ((qb1A.x + qb1A.y) + (qb1A.z + qb1A.w))) +
                              ((qc1A.x + qc1A.y) + (qc1A.z + qc1A.w));
            // ---- sums B ----
            const float SAB = (((qa0B.x + qa0B.y) + (qa0B.z + qa0B.w)) +
                               ((qb0B.x + qb0B.y) + (qb0B.z + qb0B.w))) +
                              ((qc0B.x + qc0B.y) + (qc0B.z + qc0B.w));
            const float SBB = (((qa1B.x + qa1B.y) + (qa1B.z + qa1B.w)) +
                               ((qb1B.x + qb1B.y) + (qb1B.z + qb1B.w))) +
                              ((qc1B.x + qc1B.y) + (qc1B.z + qc1B.w));

            // ---- rescale (lane 0 holds S(0) for each batch) ----
            const float s0uA = rfl(SAA);
            const float rA = fast_rcp(s0uA);
            const float s0uB = rfl(SAB);
            const float rB = fast_rcp(s0uB);

            savedSA = (i == mbA) ? SBA : savedSA;
            savedCA = (i == mbA) ? CcA : savedCA;
            savedSB = (i == mbB) ? SBB : savedSB;
            savedCB = (i == mbB) ? CcB : savedCB;
            CcA += fast_log2(s0uA);                       // off-chain
            CcB += fast_log2(s0uB);

#pragma unroll
            for (int k = 0; k < KK - 1; ++k) {
                WA0[k] = WA0[k + 1] * rA; WA1[k] = WA1[k + 1] * rA;
                WB0[k] = WB0[k + 1] * rB; WB1[k] = WB1[k + 1] * rB;
            }
            WA0[KK - 1] = SAA * rA; WA1[KK - 1] = SBA * rA;
            WB0[KK - 1] = SAB * rB; WB1[KK - 1] = SBB * rB;

            cfence();                  // order phase-2 reads before next sp writes
        };

        __builtin_amdgcn_s_setprio(1);
        block_sync();                                     // B0: panes 1..4 ready

        for (int t = 1; t <= 32; ++t) {
            const int p0 = 4 * t - 3;

            readPane(ring[0], p0, A_EA);     readPane(ring[1], p0, B_EA);
            readPane(ring[0], p0 + 1, A_EB); readPane(ring[1], p0 + 1, B_EB);

            body2(p0, A_EA, B_EA);

            readPane(ring[0], p0 + 2, A_EC); readPane(ring[1], p0 + 2, B_EC);
            readPane(ring[0], p0 + 3, A_EA); readPane(ring[1], p0 + 3, B_EA);

            body2(p0 + 1, A_EB, B_EB);
            body2(p0 + 2, A_EC, B_EC);
            body2(p0 + 3, A_EA, B_EA);

            if (t < 32) block_sync();                     // 31 tick barriers
        }

        if (l == 35) {                 // o1 = 99 -> (yp1=9): row 9 = stop_id
            atomicAdd(out, (savedCA + fast_log2(savedSA)) * LN2);
            if (bB < n_batch)
                atomicAdd(out, (savedCB + fast_log2(savedSB)) * LN2);
        }
    }
}

extern "C" void kernel_launch(void* const* d_in, const int* in_sizes, int n_in,
                              void* d_out, int out_size, void* d_ws, size_t ws_size,
                              hipStream_t stream) {
    const float* scores = (const float*)d_in[0];
    const int*   mask   = (const int*)d_in[1];
    float* out = (float*)d_out;
    const int B = in_sizes[1];   // 16

    hipMemsetAsync(out, 0, sizeof(float) * out_size, stream);

    (void)d_ws; (void)ws_size;   // unused (ws poison is unconditional harness cost)

    hscrf_pc5<<<(B + 1) / 2, 320, 0, stream>>>(scores, mask, out, B);
}

// Round 9
// 179.708 us; speedup vs baseline: 1.1210x; 1.1210x over previous
//
#include <hip/hip_runtime.h>
#include <math.h>

#define LL 128
#define TT 11
#define NP 121            // T*T (y, y_prev) pairs
#define KK 7
#define GS 20             // sp group stride (floats); group g at [g*20 .. g*20+10], pad at +11
#define SPW 240           // 11 groups*20 + dummy slots 220..226
#define NSLOT 16          // E-pane LDS ring slots (8 consumed + 8 produced per tick)
#define PANEF 1024        // floats per E pane: [m=2][pair o=128][float4]

#define LOG2E 1.4426950408889634f
#define LN2   0.6931471805599453f

__device__ __forceinline__ float fast_exp2(float x) { return __builtin_amdgcn_exp2f(x); }
__device__ __forceinline__ float fast_log2(float x) { return __builtin_amdgcn_logf(x); }
#if __has_builtin(__builtin_amdgcn_rcpf)
__device__ __forceinline__ float fast_rcp(float x) { return __builtin_amdgcn_rcpf(x); }
#else
__device__ __forceinline__ float fast_rcp(float x) { return 1.0f / x; }
#endif
__device__ __forceinline__ float rfl(float x) {
    return __int_as_float(__builtin_amdgcn_readfirstlane(__float_as_int(x)));
}
__device__ __forceinline__ void cfence() { __builtin_amdgcn_wave_barrier(); }
#define VMWAIT28() asm volatile("s_waitcnt vmcnt(28)" ::: "memory")
#define VMWAIT0()  asm volatile("s_waitcnt vmcnt(0)"  ::: "memory")
#define LGKM0()    asm volatile("s_waitcnt lgkmcnt(0)" ::: "memory")

__device__ __forceinline__ void block_sync() {
    asm volatile("" ::: "memory");
    __builtin_amdgcn_s_barrier();
    asm volatile("" ::: "memory");
}

// ---------------------------------------------------------------------------
// Producer/consumer semi-CRF forward DP, v6: round-6 machine, 8 steps/tick.
//
// Round-7 (shuffle phase-2) and round-8 (dual-batch consumer) both REGRESSED:
// every extra DS op on the consumer wave's in-order DS stream lengthens the
// serial chain 1:1. Round-6 (4 steps/tick, minimal-consumer-DS) is the best
// measured machine (177.6 us total, ~30.6 us kernel). v6 keeps its consumer
// body, producer conv, and per-step math BIT-IDENTICAL, and only scales the
// proven knob: steps/tick 4 -> 8 (ticks 32 -> 16), which round 5->6 showed
// removes barrier + producer-interference overhead without touching the chain.
//
//   - ring: 16 slots (64 KB). Consumer tick t reads panes 8t-7..8t; producers
//     write panes 8t+1..8t+8 -- complementary halves mod 16, disjoint.
//   - producers (2 waves, odd/even panes): 4 panes/tick each, 4-buffer
//     rotation (Pa..Pd), two vmcnt(28) waits per tick, issue-after-convert,
//     max 56 outstanding loads (< 63 counter limit). Load lead ~0.5-1 tick
//     (>= ~2000 cyc >> 900 cyc HBM latency).
//   - consumer: 3-buffer E rotation (EA/EB/EC), lead-2 pane prefetch placed
//     between body steps (round-6 pattern), statically unrolled 8-step tick.
//   - 16 barriers per wave incl. B0 (was 32).
// ---------------------------------------------------------------------------
__global__ __launch_bounds__(192, 1) void hscrf_pc6(const float* __restrict__ scores,
                                                    const int* __restrict__ mask,
                                                    float* __restrict__ out,
                                                    int n_batch)
{
    const int tid = threadIdx.x;
    const int l   = tid & 63;
    const int wid = tid >> 6;
    const int b   = blockIdx.x;
    if (b >= n_batch) return;

    __shared__ __align__(64) float ring[NSLOT][PANEF];   // 64 KB
    __shared__ __align__(64) float sp[SPW];

    const float* sb = scores + (size_t)b * (size_t)(LL * (size_t)LL * NP);

    const int o1  = l + 64;
    const bool val1 = (o1 < NP);
    const int o1c = val1 ? o1 : 0;

    if (wid >= 1) {
        // ============ PRODUCERS (wave1: odd panes, wave2: even panes) ========
        const int pw = wid - 1;

        // Four pane buffers (static rotation, no runtime indexing).
        float Pa0[KK], Pa1[KK], Pb0[KK], Pb1[KK];
        float Pc0[KK], Pc1[KK], Pd0[KK], Pd1[KK];

        // Coalesced gathers: pair o's raw score sits at slice[o] (o = yp*11+y).
        auto issue_pane = [&](int p, float (&a0)[KK], float (&a1)[KK]) {
#pragma unroll
            for (int k = 0; k < KK; ++k) {
                const int j = p - KK + k; const int jc = j < 0 ? 0 : j;
                const float* sl = sb + ((size_t)jc * LL + (size_t)(p - 1)) * NP;
                a0[k] = sl[l];                            // pairs 0..63
                a1[k] = sl[o1c];                          // pairs 64..120
            }
        };

        // Convert pane p to linear domain, publish to ring (split-pane layout,
        // 4x stride-16 ds_write_b128, conflict-free). Bit-identical masking.
        auto conv1 = [&](int p, const float (&a0)[KK], const float (&a1)[KK]) {
            const int slot = p & (NSLOT - 1);
            float v0[8], w1[8];
#pragma unroll
            for (int k = 0; k < KK; ++k) {
                const bool ok = (p - KK + k) >= 0;        // j >= 0 mask
                const float t0 = fast_exp2(a0[k] * LOG2E);
                const float t1 = fast_exp2(a1[k] * LOG2E);
                v0[k] = ok ? t0 : 0.0f;
                w1[k] = (ok && val1) ? t1 : 0.0f;         // o>=121 pairs -> 0
            }
            v0[7] = 0.0f; w1[7] = 0.0f;
            float4* dst = (float4*)&ring[slot][0];
            dst[l]       = make_float4(v0[0], v0[1], v0[2], v0[3]);
            dst[128 + l] = make_float4(v0[4], v0[5], v0[6], v0[7]);
            dst[64 + l]  = make_float4(w1[0], w1[1], w1[2], w1[3]);
            dst[192 + l] = make_float4(w1[4], w1[5], w1[6], w1[7]);
        };

        // Prologue: publish panes 1..8 (mine: {1,3,5,7}+pw); leave my 4 panes
        // of 9..16 in flight. Max 56 outstanding loads throughout.
        issue_pane(1 + pw, Pa0, Pa1); issue_pane(3 + pw, Pb0, Pb1);   // 28
        issue_pane(5 + pw, Pc0, Pc1); issue_pane(7 + pw, Pd0, Pd1);   // 56
        VMWAIT28();                                       // Pa,Pb done
        conv1(1 + pw, Pa0, Pa1); conv1(3 + pw, Pb0, Pb1);
        issue_pane(9 + pw, Pa0, Pa1); issue_pane(11 + pw, Pb0, Pb1);  // 56
        VMWAIT28();                                       // Pc,Pd done
        conv1(5 + pw, Pc0, Pc1); conv1(7 + pw, Pd0, Pd1);
        issue_pane(13 + pw, Pc0, Pc1); issue_pane(15 + pw, Pd0, Pd1); // 56
        LGKM0(); block_sync();                            // B0: panes 1..8 live

        // Ticks 1..14 (steady state): convert panes 8t+1..8t+8 (mine: 4),
        // issue panes 8t+9..8t+16 (mine: 4) for next tick.
        for (int t = 1; t <= 14; ++t) {
            const int base = 8 * t;
            VMWAIT28();                                   // Pa,Pb loads retired
            conv1(base + 1 + pw, Pa0, Pa1); conv1(base + 3 + pw, Pb0, Pb1);
            issue_pane(base + 9 + pw, Pa0, Pa1);
            issue_pane(base + 11 + pw, Pb0, Pb1);         // 56 outstanding
            VMWAIT28();                                   // Pc,Pd loads retired
            conv1(base + 5 + pw, Pc0, Pc1); conv1(base + 7 + pw, Pd0, Pd1);
            issue_pane(base + 13 + pw, Pc0, Pc1);
            issue_pane(base + 15 + pw, Pd0, Pd1);         // 56 outstanding
            LGKM0(); block_sync();
        }
        // Tick 15: drain; publish panes 121..128 (mine: {121,123,125,127}+pw).
        VMWAIT28();
        conv1(121 + pw, Pa0, Pa1); conv1(123 + pw, Pb0, Pb1);
        VMWAIT0();
        conv1(125 + pw, Pc0, Pc1); conv1(127 + pw, Pd0, Pd1);
        LGKM0(); block_sync();                            // 16 barriers incl. B0
    } else {
        // ================= CONSUMER (round-6 body, verbatim) =================
        // Relabeled decode: pair o = yp*11 + y.
        const int y0 = l % TT,   yp0 = l / TT;
        const int y1 = o1c % TT, yp1 = o1c / TT;
        const int i0w = y0 * GS + yp0;                    // group y, position yp
        const int i1w = val1 ? (y1 * GS + yp1) : (220 + (l - 57));

        if (l < TT) sp[l * GS + 11] = 0.0f;               // zero pad for b128 phase-2

        const int mb = mask[b];

        float W0[KK], W1[KK];
#pragma unroll
        for (int k = 0; k < KK; ++k) { W0[k] = 0.0f; W1[k] = 0.0f; }
        W0[KK - 1] = (yp0 == TT - 1) ? 1.0f : 0.0f;
        W1[KK - 1] = (val1 && yp1 == TT - 1) ? 1.0f : 0.0f;

        float Cc = 0.0f;
        float savedS = 1.0f;                              // SB snapshot at i==mb
        float savedC = 0.0f;                              // Cc snapshot at i==mb

        struct E4 { float4 a0, a1, b0, b1; };
        E4 EA, EB, EC;

        auto readPane = [&](int p, E4& d) {
            const float4* b16 = (const float4*)&ring[p & (NSLOT - 1)][0];
            d.a0 = b16[l];      d.a1 = b16[128 + l];
            d.b0 = b16[64 + l]; d.b1 = b16[192 + l];
        };

        auto body = [&](int i, const E4& E) {
            // ---- phase 1: 7 FMAs per pair (tree), sp write ----
            float p0 = fmaf(E.a0.x, W0[0], E.a0.y * W0[1]);
            float q0 = fmaf(E.a0.z, W0[2], E.a0.w * W0[3]);
            float u0 = fmaf(E.a1.x, W0[4], E.a1.y * W0[5]);
            float s0 = (p0 + q0) + fmaf(E.a1.z, W0[6], u0);
            float p1 = fmaf(E.b0.x, W1[0], E.b0.y * W1[1]);
            float q1 = fmaf(E.b0.z, W1[2], E.b0.w * W1[3]);
            float u1 = fmaf(E.b1.x, W1[4], E.b1.y * W1[5]);
            float s1 = (p1 + q1) + fmaf(E.b1.z, W1[6], u1);
            sp[i0w] = s0;
            sp[i1w] = s1;

            cfence();                  // DS pipe in-order per wave

            // ---- phase 2 reads (chain-critical) ----
            const float4 qa0 = *(const float4*)(sp + yp0 * GS);
            const float4 qb0 = *(const float4*)(sp + yp0 * GS + 4);
            const float4 qc0 = *(const float4*)(sp + yp0 * GS + 8);
            const float4 qa1 = *(const float4*)(sp + yp1 * GS);
            const float4 qb1 = *(const float4*)(sp + yp1 * GS + 4);
            const float4 qc1 = *(const float4*)(sp + yp1 * GS + 8);

            // ---- phase-2 sums: SA = S(yp0), SB = S(yp1) ----
            const float SA = (((qa0.x + qa0.y) + (qa0.z + qa0.w)) +
                              ((qb0.x + qb0.y) + (qb0.z + qb0.w))) +
                             ((qc0.x + qc0.y) + (qc0.z + qc0.w));
            const float SB = (((qa1.x + qa1.y) + (qa1.z + qa1.w)) +
                              ((qb1.x + qb1.y) + (qb1.z + qb1.w))) +
                             ((qc1.x + qc1.y) + (qc1.z + qc1.w));

            // ---- rescale: r = 1/S(0) (lane 0: yp0 == 0) ----
            const float s0u = rfl(SA);
            const float r = fast_rcp(s0u);

            // snapshot for the final readout (single log2 at kernel end)
            savedS = (i == mb) ? SB : savedS;
            savedC = (i == mb) ? Cc : savedC;
            Cc += fast_log2(s0u);                         // off-chain

#pragma unroll
            for (int k = 0; k < KK - 1; ++k) { W0[k] = W0[k + 1] * r; W1[k] = W1[k + 1] * r; }
            W0[KK - 1] = SA * r;
            W1[KK - 1] = SB * r;

            cfence();                  // order phase-2 reads before next sp writes
        };

        __builtin_amdgcn_s_setprio(1);
        block_sync();                                     // B0: panes 1..8 ready

        for (int t = 1; t <= 16; ++t) {
            const int p0 = 8 * t - 7;

            // 3-buffer rotation, lead-2 prefetch (round-6 pattern, 8 steps).
            readPane(p0, EA);
            readPane(p0 + 1, EB);
            body(p0,     EA); readPane(p0 + 2, EC);
            body(p0 + 1, EB); readPane(p0 + 3, EA);
            body(p0 + 2, EC); readPane(p0 + 4, EB);
            body(p0 + 3, EA); readPane(p0 + 5, EC);
            body(p0 + 4, EB); readPane(p0 + 6, EA);
            body(p0 + 5, EC); readPane(p0 + 7, EB);
            body(p0 + 6, EA);
            body(p0 + 7, EB);

            if (t < 16) block_sync();  // 15 tick barriers (+B0 = 16)
        }

        if (l == 35) {                 // o1 = 99 -> (yp1=9): row 9 = stop_id
            atomicAdd(out, (savedC + fast_log2(savedS)) * LN2);
        }
    }
}

extern "C" void kernel_launch(void* const* d_in, const int* in_sizes, int n_in,
                              void* d_out, int out_size, void* d_ws, size_t ws_size,
                              hipStream_t stream) {
    const float* scores = (const float*)d_in[0];
    const int*   mask   = (const int*)d_in[1];
    float* out = (float*)d_out;
    const int B = in_sizes[1];   // 16

    hipMemsetAsync(out, 0, sizeof(float) * out_size, stream);

    (void)d_ws; (void)ws_size;   // unused (ws poison is unconditional harness cost)

    hscrf_pc6<<<B, 192, 0, stream>>>(scores, mask, out, B);
}